// Round 2
// baseline (1129.217 us; speedup 1.0000x reference)
//
#include <hip/hip_runtime.h>
#include <hip/hip_bf16.h>

// EdgeFFN: out[e] = relu(concat(x[src[e]], x[dst[e]]) @ W1 + b1) @ W2 + b2
// E=640000, IN=128, CAT=256, HID=256, OUT=64

#define N_EDGES_C 640000
#define N_NODES_C 100000
#define IN_DIM_C  128
#define CAT_DIM_C 256
#define HIDDEN_C  256
#define OUT_DIM_C 64
#define BM        64    // edges per tile
#define LDA       264   // padded LDS row: 528B stride -> banks 4r%32, 2-way max (free)
#define TPB_TILES 5     // tiles per block
#define GRID_MAIN 2000  // 2000 * 5 * 64 = 640000 exactly

typedef __attribute__((ext_vector_type(8))) short bf16x8;
typedef __attribute__((ext_vector_type(4))) float f32x4;

__device__ __forceinline__ ushort f2bs(float f) {
  union { __hip_bfloat16 h; ushort u; } c;
  c.h = __float2bfloat16(f);
  return c.u;
}

// ---- prep: cast node features f32 -> bf16 (vectorized 8/thread) ----
__global__ __launch_bounds__(256) void cast_x_kernel(const float* __restrict__ x,
                                                     ushort* __restrict__ xb) {
  const int i = blockIdx.x * 256 + threadIdx.x;
  const float4 v0 = reinterpret_cast<const float4*>(x)[2 * i];
  const float4 v1 = reinterpret_cast<const float4*>(x)[2 * i + 1];
  uint4 o;
  o.x = (unsigned)f2bs(v0.x) | ((unsigned)f2bs(v0.y) << 16);
  o.y = (unsigned)f2bs(v0.z) | ((unsigned)f2bs(v0.w) << 16);
  o.z = (unsigned)f2bs(v1.x) | ((unsigned)f2bs(v1.y) << 16);
  o.w = (unsigned)f2bs(v1.z) | ((unsigned)f2bs(v1.w) << 16);
  reinterpret_cast<uint4*>(xb)[i] = o;
}

// ---- prep: transpose + cast weights: W1t[n][k], W2t[o][k] ----
__global__ __launch_bounds__(256) void prep_w_kernel(const float* __restrict__ W1,
                                                     const float* __restrict__ W2,
                                                     ushort* __restrict__ W1t,
                                                     ushort* __restrict__ W2t) {
  const int i = blockIdx.x * 256 + threadIdx.x;
  if (i < HIDDEN_C * CAT_DIM_C) {
    const int n = i >> 8, k = i & 255;
    W1t[i] = f2bs(W1[k * HIDDEN_C + n]);
  } else {
    const int j = i - HIDDEN_C * CAT_DIM_C;
    const int o = j >> 8, k = j & 255;
    W2t[j] = f2bs(W2[k * OUT_DIM_C + o]);
  }
}

// ---- main fused kernel, pipelined over TPB_TILES tiles ----
// 256 thr / 4 waves. Wave w: GEMM1 cols [w*64,(w+1)*64), GEMM2 edges [w*16,(w+1)*16).
// Pipeline: gather(t+1) issued right after GEMM1(t) MFMAs; ei prefetched 2 tiles ahead.
template <int USE_XB>
__global__ __launch_bounds__(256, 4) void edge_ffn_kernel(
    const ushort* __restrict__ xb, const float* __restrict__ xf,
    const int* __restrict__ ei,
    const ushort* __restrict__ W1t, const float* __restrict__ b1,
    const ushort* __restrict__ W2t, const float* __restrict__ b2,
    float* __restrict__ out) {
  __shared__ ushort A[BM * LDA];   // 33,792 B; reused for H after GEMM1

  const int tid  = threadIdx.x;
  const int lane = tid & 63;
  const int w    = tid >> 6;
  const int l15  = lane & 15;
  const int lg   = lane >> 4;
  const int li   = tid & 15;        // staging: 16 lanes cover one 128-elem half-row
  const int hr0  = tid >> 4;        // staging half-row base
  const int tile0 = blockIdx.x * TPB_TILES;

  // hoisted invariants
  float b1v[4], b2v[4];
#pragma unroll
  for (int n = 0; n < 4; ++n) {
    b1v[n] = b1[w * 64 + n * 16 + l15];
    b2v[n] = b2[n * 16 + l15];
  }

  int   nid[8];
  uint4 rbuf[8];

  // --- helpers as macros to keep everything in registers ---
#define LOAD_NID(tt)                                                        \
  {                                                                         \
    const int e0n = (tt) * BM;                                              \
    _Pragma("unroll") for (int it = 0; it < 8; ++it) {                      \
      const int hr = hr0 + it * 16;                                         \
      nid[it] = ei[(hr & 1) * N_EDGES_C + e0n + (hr >> 1)];                 \
    }                                                                       \
  }

#define GATHER()                                                            \
  {                                                                         \
    _Pragma("unroll") for (int it = 0; it < 8; ++it) {                      \
      if (USE_XB) {                                                         \
        rbuf[it] = *reinterpret_cast<const uint4*>(                         \
            xb + (size_t)nid[it] * IN_DIM_C + li * 8);                      \
      } else {                                                              \
        const float4* row =                                                 \
            reinterpret_cast<const float4*>(xf + (size_t)nid[it] * IN_DIM_C);\
        const float4 v0 = row[li * 2];                                      \
        const float4 v1 = row[li * 2 + 1];                                  \
        uint4 o;                                                            \
        o.x = (unsigned)f2bs(v0.x) | ((unsigned)f2bs(v0.y) << 16);          \
        o.y = (unsigned)f2bs(v0.z) | ((unsigned)f2bs(v0.w) << 16);          \
        o.z = (unsigned)f2bs(v1.x) | ((unsigned)f2bs(v1.y) << 16);          \
        o.w = (unsigned)f2bs(v1.z) | ((unsigned)f2bs(v1.w) << 16);          \
        rbuf[it] = o;                                                       \
      }                                                                     \
    }                                                                       \
  }

  // --- prologue: fill pipeline ---
  LOAD_NID(tile0);
  GATHER();                 // tile 0 rows -> rbuf
  LOAD_NID(tile0 + 1);      // indices for tile 1

  for (int t = 0; t < TPB_TILES; ++t) {
    const int e0 = (tile0 + t) * BM;

    __syncthreads();        // prev GEMM2 done reading A/H region
    // ---------- stage tile t from registers into LDS ----------
#pragma unroll
    for (int it = 0; it < 8; ++it) {
      const int hr = hr0 + it * 16;
      *reinterpret_cast<uint4*>(&A[(hr >> 1) * LDA + (hr & 1) * IN_DIM_C + li * 8]) =
          rbuf[it];
    }
    __syncthreads();        // A ready

    // ---------- GEMM1: h[64 x 256] = A @ W1 ----------
    f32x4 acc[4][4];
#pragma unroll
    for (int m = 0; m < 4; ++m)
#pragma unroll
      for (int n = 0; n < 4; ++n) acc[m][n] = (f32x4){0.f, 0.f, 0.f, 0.f};

#pragma unroll
    for (int ks = 0; ks < 8; ++ks) {
      const int kb = ks * 32 + lg * 8;
      bf16x8 a[4], b[4];
#pragma unroll
      for (int m = 0; m < 4; ++m)
        a[m] = *reinterpret_cast<const bf16x8*>(&A[(m * 16 + l15) * LDA + kb]);
#pragma unroll
      for (int n = 0; n < 4; ++n)
        b[n] = *reinterpret_cast<const bf16x8*>(W1t + (w * 64 + n * 16 + l15) * CAT_DIM_C + kb);
#pragma unroll
      for (int m = 0; m < 4; ++m)
#pragma unroll
        for (int n = 0; n < 4; ++n)
          acc[m][n] = __builtin_amdgcn_mfma_f32_16x16x32_bf16(a[m], b[n], acc[m][n], 0, 0, 0);
    }

    // ---------- issue next tile's gather NOW (hidden under H + GEMM2) ----------
    if (t + 1 < TPB_TILES) GATHER();
    if (t + 2 < TPB_TILES) LOAD_NID(tile0 + t + 2);

    __syncthreads();        // all waves done reading A before overwrite with H

    // ---------- bias + relu, h -> bf16 into LDS (reuse A) ----------
#pragma unroll
    for (int m = 0; m < 4; ++m)
#pragma unroll
      for (int n = 0; n < 4; ++n)
#pragma unroll
        for (int i = 0; i < 4; ++i) {
          float v = acc[m][n][i] + b1v[n];
          v = v > 0.f ? v : 0.f;
          A[(m * 16 + lg * 4 + i) * LDA + w * 64 + n * 16 + l15] = f2bs(v);
        }
    __syncthreads();        // H visible

    // ---------- GEMM2: out[64 x 64] = H @ W2 ----------
    f32x4 acc2[4];
#pragma unroll
    for (int n = 0; n < 4; ++n) acc2[n] = (f32x4){0.f, 0.f, 0.f, 0.f};

#pragma unroll
    for (int ks = 0; ks < 8; ++ks) {
      const int kb = ks * 32 + lg * 8;
      const bf16x8 a2 = *reinterpret_cast<const bf16x8*>(&A[(w * 16 + l15) * LDA + kb]);
#pragma unroll
      for (int n = 0; n < 4; ++n) {
        const bf16x8 bb =
            *reinterpret_cast<const bf16x8*>(W2t + (n * 16 + l15) * HIDDEN_C + kb);
        acc2[n] = __builtin_amdgcn_mfma_f32_16x16x32_bf16(a2, bb, acc2[n], 0, 0, 0);
      }
    }

    // ---------- epilogue: + b2, store f32 ----------
#pragma unroll
    for (int n = 0; n < 4; ++n)
#pragma unroll
      for (int i = 0; i < 4; ++i)
        out[(size_t)(e0 + w * 16 + lg * 4 + i) * OUT_DIM_C + n * 16 + l15] =
            acc2[n][i] + b2v[n];
  }
#undef LOAD_NID
#undef GATHER
}

extern "C" void kernel_launch(void* const* d_in, const int* in_sizes, int n_in,
                              void* d_out, int out_size, void* d_ws, size_t ws_size,
                              hipStream_t stream) {
  const float* x  = (const float*)d_in[0];
  const int*   ei = (const int*)d_in[1];
  const float* W1 = (const float*)d_in[2];
  const float* b1 = (const float*)d_in[3];
  const float* W2 = (const float*)d_in[4];
  const float* b2 = (const float*)d_in[5];
  float* out = (float*)d_out;

  const size_t xb_elems  = (size_t)N_NODES_C * IN_DIM_C;   // 12.8M bf16
  const size_t w1t_elems = HIDDEN_C * CAT_DIM_C;
  const size_t w2t_elems = OUT_DIM_C * HIDDEN_C;
  const size_t need_full = (xb_elems + w1t_elems + w2t_elems) * sizeof(ushort);

  ushort* base = (ushort*)d_ws;
  if (ws_size >= need_full) {
    ushort* xbp = base;
    ushort* W1t = xbp + xb_elems;
    ushort* W2t = W1t + w1t_elems;
    cast_x_kernel<<<(N_NODES_C * IN_DIM_C) / (256 * 8), 256, 0, stream>>>(x, xbp);
    prep_w_kernel<<<(HIDDEN_C * CAT_DIM_C + OUT_DIM_C * HIDDEN_C) / 256, 256, 0, stream>>>(
        W1, W2, W1t, W2t);
    edge_ffn_kernel<1><<<GRID_MAIN, 256, 0, stream>>>(xbp, x, ei, W1t, b1, W2t, b2, out);
  } else {
    ushort* W1t = base;
    ushort* W2t = W1t + w1t_elems;
    prep_w_kernel<<<(HIDDEN_C * CAT_DIM_C + OUT_DIM_C * HIDDEN_C) / 256, 256, 0, stream>>>(
        W1, W2, W1t, W2t);
    edge_ffn_kernel<0><<<GRID_MAIN, 256, 0, stream>>>(nullptr, x, ei, W1t, b1, W2t, b2, out);
  }
}

// Round 3
// 796.005 us; speedup vs baseline: 1.4186x; 1.4186x over previous
//
#include <hip/hip_runtime.h>
#include <hip/hip_bf16.h>

// EdgeFFN: out[e] = relu(concat(x[src[e]], x[dst[e]]) @ W1 + b1) @ W2 + b2
// E=640000, IN=128, CAT=256, HID=256, OUT=64

#define N_EDGES_C 640000
#define N_NODES_C 100000
#define IN_DIM_C  128
#define CAT_DIM_C 256
#define HIDDEN_C  256
#define OUT_DIM_C 64
#define BM        64     // edges per tile
#define TPB_TILES 5      // tiles per block
#define GRID_MAIN 2000   // 2000 * 5 * 64 = 640000 exactly

typedef __attribute__((ext_vector_type(8))) short bf16x8;
typedef __attribute__((ext_vector_type(4))) float f32x4;

__device__ __forceinline__ ushort f2bs(float f) {
  union { __hip_bfloat16 h; ushort u; } c;
  c.h = __float2bfloat16(f);
  return c.u;
}

// XOR swizzle on 16B blocks within a [64][256]-ushort tile (rule #21: applied
// to the pre-swizzled global SOURCE of global_load_lds and to every LDS read/
// write; LDS destination itself stays linear).
//   element (row, col)  -> ushort idx = row*256 + (((col>>3) ^ (row&7))<<3) + (col&7)
__device__ __forceinline__ int swz_idx(int row, int col) {
  return row * 256 + ((((col >> 3) ^ (row & 7)) << 3) | (col & 7));
}
// 16B-block form: cb in [0,32)
__device__ __forceinline__ int swz_blk_idx(int row, int cb) {
  return row * 256 + ((cb ^ (row & 7)) << 3);
}

typedef __attribute__((address_space(1))) const void* as1cp;
typedef __attribute__((address_space(3))) void* as3p;
__device__ __forceinline__ void async_cp16(const void* g, void* l) {
  __builtin_amdgcn_global_load_lds((as1cp)g, (as3p)l, 16, 0, 0);
}

// ---- prep: cast node features f32 -> bf16 (vectorized 8/thread) ----
__global__ __launch_bounds__(256) void cast_x_kernel(const float* __restrict__ x,
                                                     ushort* __restrict__ xb) {
  const int i = blockIdx.x * 256 + threadIdx.x;
  const float4 v0 = reinterpret_cast<const float4*>(x)[2 * i];
  const float4 v1 = reinterpret_cast<const float4*>(x)[2 * i + 1];
  uint4 o;
  o.x = (unsigned)f2bs(v0.x) | ((unsigned)f2bs(v0.y) << 16);
  o.y = (unsigned)f2bs(v0.z) | ((unsigned)f2bs(v0.w) << 16);
  o.z = (unsigned)f2bs(v1.x) | ((unsigned)f2bs(v1.y) << 16);
  o.w = (unsigned)f2bs(v1.z) | ((unsigned)f2bs(v1.w) << 16);
  reinterpret_cast<uint4*>(xb)[i] = o;
}

// ---- prep: transpose + cast weights: W1t[n][k], W2t[o][k] ----
__global__ __launch_bounds__(256) void prep_w_kernel(const float* __restrict__ W1,
                                                     const float* __restrict__ W2,
                                                     ushort* __restrict__ W1t,
                                                     ushort* __restrict__ W2t) {
  const int i = blockIdx.x * 256 + threadIdx.x;
  if (i < HIDDEN_C * CAT_DIM_C) {
    const int n = i >> 8, k = i & 255;
    W1t[i] = f2bs(W1[k * HIDDEN_C + n]);
  } else {
    const int j = i - HIDDEN_C * CAT_DIM_C;
    const int o = j >> 8, k = j & 255;
    W2t[j] = f2bs(W2[k * OUT_DIM_C + o]);
  }
}

// ---- main fused kernel: DMA-gathered, LDS double-buffered, tile-pipelined ----
// 256 thr / 4 waves. Wave w: GEMM1 cols [w*64,(w+1)*64), GEMM2 edges [w*16,(w+1)*16).
// Buffers: Ab[cur] = input tile t (then overwritten by H(t) after GEMM1);
//          Ab[cur^1] = free at tile start -> gather(t+1) DMA lands there.
__global__ __launch_bounds__(256, 2) void edge_ffn_kernel(
    const ushort* __restrict__ xb, const int* __restrict__ ei,
    const ushort* __restrict__ W1t, const float* __restrict__ b1,
    const ushort* __restrict__ W2t, const float* __restrict__ b2,
    float* __restrict__ out) {
  __shared__ ushort Ab[2][BM * 256];   // 2 x 32 KiB

  const int tid   = threadIdx.x;
  const int lane  = tid & 63;
  const int w     = tid >> 6;
  const int l15   = lane & 15;
  const int lg    = lane >> 4;
  const int li    = tid & 15;   // staging: 16 lanes per 128-elem half-row
  const int hr0   = tid >> 4;   // staging half-row base (0..15)
  const int tile0 = blockIdx.x * TPB_TILES;

  float b1v[4], b2v[4];
#pragma unroll
  for (int n = 0; n < 4; ++n) {
    b1v[n] = b1[w * 64 + n * 16 + l15];
    b2v[n] = b2[n * 16 + l15];
  }

  int nid[8];

#define LOAD_NID(tt)                                                         \
  {                                                                          \
    const int e0n = (tt) * BM;                                               \
    _Pragma("unroll") for (int it = 0; it < 8; ++it) {                       \
      const int hr = hr0 + it * 16;                                          \
      nid[it] = ei[(hr & 1) * N_EDGES_C + e0n + (hr >> 1)];                  \
    }                                                                        \
  }

  // DMA gather into buffer nb. LDS dest is linear (wave base + lane*16B);
  // the bank-conflict swizzle is applied on the per-lane GLOBAL source.
#define GATHER_DMA(nb)                                                       \
  {                                                                          \
    _Pragma("unroll") for (int it = 0; it < 8; ++it) {                       \
      const int hr   = hr0 + it * 16;                                        \
      const int edge = hr >> 1;                                              \
      const int lip  = li ^ (edge & 7);                                      \
      const ushort* gsrc = xb + (size_t)nid[it] * IN_DIM_C + lip * 8;        \
      ushort* ldst = &Ab[nb][hr * 128 + li * 8];                             \
      async_cp16(gsrc, ldst);                                                \
    }                                                                        \
  }

  // ---- prologue: tile 0 gather (unhidden, once), tile-1 indices prefetched ----
  LOAD_NID(tile0);
  GATHER_DMA(0);
  LOAD_NID(tile0 + 1);
  __syncthreads();            // drains vmcnt -> Ab[0] ready
  int cur = 0;

  for (int t = 0; t < TPB_TILES; ++t) {
    const int e0 = (tile0 + t) * BM;

    // ---- issue next tile's DMA gather immediately (Ab[cur^1] is free) ----
    if (t + 1 < TPB_TILES) {
      GATHER_DMA(cur ^ 1);
      if (t + 2 < TPB_TILES) LOAD_NID(tile0 + t + 2);
    }

    // ---------- GEMM1: h[64 x 256] = A @ W1 ----------
    f32x4 acc[4][4];
#pragma unroll
    for (int m = 0; m < 4; ++m)
#pragma unroll
      for (int n = 0; n < 4; ++n) acc[m][n] = (f32x4){0.f, 0.f, 0.f, 0.f};

#pragma unroll
    for (int ks = 0; ks < 8; ++ks) {
      const int kcb = ks * 4 + lg;      // 16B block index in k
      bf16x8 a[4], b[4];
#pragma unroll
      for (int m = 0; m < 4; ++m)
        a[m] = *reinterpret_cast<const bf16x8*>(&Ab[cur][swz_blk_idx(m * 16 + l15, kcb)]);
#pragma unroll
      for (int n = 0; n < 4; ++n)
        b[n] = *reinterpret_cast<const bf16x8*>(W1t + (w * 64 + n * 16 + l15) * CAT_DIM_C +
                                                ks * 32 + lg * 8);
#pragma unroll
      for (int m = 0; m < 4; ++m)
#pragma unroll
        for (int n = 0; n < 4; ++n)
          acc[m][n] = __builtin_amdgcn_mfma_f32_16x16x32_bf16(a[m], b[n], acc[m][n], 0, 0, 0);
    }

    __syncthreads();   // GEMM1 A-reads done (also drains gather(t+1), ~hidden)

    // ---------- bias + relu, H -> bf16 into Ab[cur] (swizzled) ----------
#pragma unroll
    for (int m = 0; m < 4; ++m)
#pragma unroll
      for (int n = 0; n < 4; ++n)
#pragma unroll
        for (int i = 0; i < 4; ++i) {
          float v = acc[m][n][i] + b1v[n];
          v = v > 0.f ? v : 0.f;
          Ab[cur][swz_idx(m * 16 + lg * 4 + i, w * 64 + n * 16 + l15)] = f2bs(v);
        }
    __syncthreads();   // H visible

    // ---------- GEMM2: out[64 x 64] = H @ W2 ----------
    f32x4 acc2[4];
#pragma unroll
    for (int n = 0; n < 4; ++n) acc2[n] = (f32x4){0.f, 0.f, 0.f, 0.f};

#pragma unroll
    for (int ks = 0; ks < 8; ++ks) {
      const bf16x8 a2 =
          *reinterpret_cast<const bf16x8*>(&Ab[cur][swz_blk_idx(w * 16 + l15, ks * 4 + lg)]);
#pragma unroll
      for (int n = 0; n < 4; ++n) {
        const bf16x8 bb =
            *reinterpret_cast<const bf16x8*>(W2t + (n * 16 + l15) * HIDDEN_C + ks * 32 + lg * 8);
        acc2[n] = __builtin_amdgcn_mfma_f32_16x16x32_bf16(a2, bb, acc2[n], 0, 0, 0);
      }
    }

    // ---------- epilogue: + b2, store f32 ----------
#pragma unroll
    for (int n = 0; n < 4; ++n)
#pragma unroll
      for (int i = 0; i < 4; ++i)
        out[(size_t)(e0 + w * 16 + lg * 4 + i) * OUT_DIM_C + n * 16 + l15] =
            acc2[n][i] + b2v[n];

    __syncthreads();   // close tile: H reads done, gather(t+1) drained
    cur ^= 1;
  }
#undef LOAD_NID
#undef GATHER_DMA
}

// ---- fallback (ws too small for bf16 x cache): round-1 proven kernel, f32 gather ----
#define LDA_FB 264
__global__ __launch_bounds__(256) void edge_ffn_fb(
    const float* __restrict__ xf, const int* __restrict__ ei,
    const ushort* __restrict__ W1t, const float* __restrict__ b1,
    const ushort* __restrict__ W2t, const float* __restrict__ b2,
    float* __restrict__ out) {
  __shared__ ushort A[BM * LDA_FB];
  const int tid = threadIdx.x, lane = tid & 63, w = tid >> 6;
  const int e0 = blockIdx.x * BM, l15 = lane & 15, lg = lane >> 4;
  {
    const int li = tid & 15, hr0 = tid >> 4;
#pragma unroll
    for (int it = 0; it < 8; ++it) {
      const int hr = hr0 + it * 16, edge = hr >> 1, which = hr & 1;
      const int node = ei[which * N_EDGES_C + e0 + edge];
      const float4* row = reinterpret_cast<const float4*>(xf + (size_t)node * IN_DIM_C);
      const float4 v0 = row[li * 2], v1 = row[li * 2 + 1];
      uint4 o;
      o.x = (unsigned)f2bs(v0.x) | ((unsigned)f2bs(v0.y) << 16);
      o.y = (unsigned)f2bs(v0.z) | ((unsigned)f2bs(v0.w) << 16);
      o.z = (unsigned)f2bs(v1.x) | ((unsigned)f2bs(v1.y) << 16);
      o.w = (unsigned)f2bs(v1.z) | ((unsigned)f2bs(v1.w) << 16);
      *reinterpret_cast<uint4*>(&A[edge * LDA_FB + which * IN_DIM_C + li * 8]) = o;
    }
  }
  __syncthreads();
  f32x4 acc[4][4];
#pragma unroll
  for (int m = 0; m < 4; ++m)
#pragma unroll
    for (int n = 0; n < 4; ++n) acc[m][n] = (f32x4){0.f, 0.f, 0.f, 0.f};
#pragma unroll
  for (int ks = 0; ks < 8; ++ks) {
    const int kb = ks * 32 + lg * 8;
    bf16x8 a[4], b[4];
#pragma unroll
    for (int m = 0; m < 4; ++m)
      a[m] = *reinterpret_cast<const bf16x8*>(&A[(m * 16 + l15) * LDA_FB + kb]);
#pragma unroll
    for (int n = 0; n < 4; ++n)
      b[n] = *reinterpret_cast<const bf16x8*>(W1t + (w * 64 + n * 16 + l15) * CAT_DIM_C + kb);
#pragma unroll
    for (int m = 0; m < 4; ++m)
#pragma unroll
      for (int n = 0; n < 4; ++n)
        acc[m][n] = __builtin_amdgcn_mfma_f32_16x16x32_bf16(a[m], b[n], acc[m][n], 0, 0, 0);
  }
  float b1v[4], b2v[4];
#pragma unroll
  for (int n = 0; n < 4; ++n) { b1v[n] = b1[w * 64 + n * 16 + l15]; b2v[n] = b2[n * 16 + l15]; }
  __syncthreads();
#pragma unroll
  for (int m = 0; m < 4; ++m)
#pragma unroll
    for (int n = 0; n < 4; ++n)
#pragma unroll
      for (int i = 0; i < 4; ++i) {
        float v = acc[m][n][i] + b1v[n];
        v = v > 0.f ? v : 0.f;
        A[(m * 16 + lg * 4 + i) * LDA_FB + w * 64 + n * 16 + l15] = f2bs(v);
      }
  __syncthreads();
  f32x4 acc2[4];
#pragma unroll
  for (int n = 0; n < 4; ++n) acc2[n] = (f32x4){0.f, 0.f, 0.f, 0.f};
#pragma unroll
  for (int ks = 0; ks < 8; ++ks) {
    const int kb = ks * 32 + lg * 8;
    const bf16x8 a2 = *reinterpret_cast<const bf16x8*>(&A[(w * 16 + l15) * LDA_FB + kb]);
#pragma unroll
    for (int n = 0; n < 4; ++n) {
      const bf16x8 bb = *reinterpret_cast<const bf16x8*>(W2t + (n * 16 + l15) * HIDDEN_C + kb);
      acc2[n] = __builtin_amdgcn_mfma_f32_16x16x32_bf16(a2, bb, acc2[n], 0, 0, 0);
    }
  }
#pragma unroll
  for (int n = 0; n < 4; ++n)
#pragma unroll
    for (int i = 0; i < 4; ++i)
      out[(size_t)(e0 + w * 16 + lg * 4 + i) * OUT_DIM_C + n * 16 + l15] = acc2[n][i] + b2v[n];
}

extern "C" void kernel_launch(void* const* d_in, const int* in_sizes, int n_in,
                              void* d_out, int out_size, void* d_ws, size_t ws_size,
                              hipStream_t stream) {
  const float* x  = (const float*)d_in[0];
  const int*   ei = (const int*)d_in[1];
  const float* W1 = (const float*)d_in[2];
  const float* b1 = (const float*)d_in[3];
  const float* W2 = (const float*)d_in[4];
  const float* b2 = (const float*)d_in[5];
  float* out = (float*)d_out;

  const size_t xb_elems  = (size_t)N_NODES_C * IN_DIM_C;
  const size_t w1t_elems = HIDDEN_C * CAT_DIM_C;
  const size_t w2t_elems = OUT_DIM_C * HIDDEN_C;
  const size_t need_full = (xb_elems + w1t_elems + w2t_elems) * sizeof(ushort);

  ushort* base = (ushort*)d_ws;
  if (ws_size >= need_full) {
    ushort* xbp = base;
    ushort* W1t = xbp + xb_elems;
    ushort* W2t = W1t + w1t_elems;
    cast_x_kernel<<<(N_NODES_C * IN_DIM_C) / (256 * 8), 256, 0, stream>>>(x, xbp);
    prep_w_kernel<<<(HIDDEN_C * CAT_DIM_C + OUT_DIM_C * HIDDEN_C) / 256, 256, 0, stream>>>(
        W1, W2, W1t, W2t);
    edge_ffn_kernel<<<GRID_MAIN, 256, 0, stream>>>(xbp, ei, W1t, b1, W2t, b2, out);
  } else {
    ushort* W1t = base;
    ushort* W2t = W1t + w1t_elems;
    prep_w_kernel<<<(HIDDEN_C * CAT_DIM_C + OUT_DIM_C * HIDDEN_C) / 256, 256, 0, stream>>>(
        W1, W2, W1t, W2t);
    edge_ffn_fb<<<N_EDGES_C / BM, 256, 0, stream>>>(x, ei, W1t, b1, W2t, b2, out);
  }
}